// Round 1
// baseline (328.131 us; speedup 1.0000x reference)
//
#include <hip/hip_runtime.h>
#include <hip/hip_bf16.h>

#define NN 100000
#define NE 800000
#define FIN 96
#define FH 128
#define FC 64
#define NB_SCAN 49  // ceil(NN/2048)

typedef unsigned short u16;
typedef unsigned int u32;
typedef __attribute__((ext_vector_type(8))) __bf16 bf16x8;
typedef __attribute__((ext_vector_type(4))) float f32x4;

__device__ __forceinline__ float bf2f(u16 u) {
    u32 x = ((u32)u) << 16;
    return __builtin_bit_cast(float, x);
}
__device__ __forceinline__ u16 f2bf(float f) {
    u32 u = __builtin_bit_cast(u32, f);
    u += 0x7fffu + ((u >> 16) & 1u);
    return (u16)(u >> 16);
}
__device__ __forceinline__ void load8f(const u16* p, float* o) {
    uint4 pk = *(const uint4*)p;
    o[0] = bf2f((u16)pk.x); o[1] = bf2f((u16)(pk.x >> 16));
    o[2] = bf2f((u16)pk.y); o[3] = bf2f((u16)(pk.y >> 16));
    o[4] = bf2f((u16)pk.z); o[5] = bf2f((u16)(pk.z >> 16));
    o[6] = bf2f((u16)pk.w); o[7] = bf2f((u16)(pk.w >> 16));
}
__device__ __forceinline__ void store8bf(u16* p, const float* v) {
    uint4 pk;
    pk.x = (u32)f2bf(v[0]) | ((u32)f2bf(v[1]) << 16);
    pk.y = (u32)f2bf(v[2]) | ((u32)f2bf(v[3]) << 16);
    pk.z = (u32)f2bf(v[4]) | ((u32)f2bf(v[5]) << 16);
    pk.w = (u32)f2bf(v[6]) | ((u32)f2bf(v[7]) << 16);
    *(uint4*)p = pk;
}

// ---------- degree / norm ----------
__global__ void k_hist(const int* __restrict__ dst, int* __restrict__ cnt) {
    int e = blockIdx.x * 256 + threadIdx.x;
    if (e < NE) atomicAdd(&cnt[dst[e]], 1);
}
__global__ void k_dinv(const int* __restrict__ cnt, float* __restrict__ dinv) {
    int i = blockIdx.x * 256 + threadIdx.x;
    if (i < NN) dinv[i] = rsqrtf((float)cnt[i] + 1.0f);
}

// ---------- exclusive scan of cnt -> row_start ----------
__global__ void k_scan_a(const int* __restrict__ cnt, int* __restrict__ row_start,
                         int* __restrict__ blk_sums) {
    __shared__ int sh[256];
    int t = threadIdx.x;
    int base = blockIdx.x * 2048 + t * 8;
    int v[8]; int s = 0;
#pragma unroll
    for (int j = 0; j < 8; j++) {
        int idx = base + j;
        int c = (idx < NN) ? cnt[idx] : 0;
        v[j] = s; s += c;
    }
    sh[t] = s;
    __syncthreads();
    for (int off = 1; off < 256; off <<= 1) {
        int x = (t >= off) ? sh[t - off] : 0;
        __syncthreads();
        sh[t] += x;
        __syncthreads();
    }
    int excl = sh[t] - s;
#pragma unroll
    for (int j = 0; j < 8; j++) {
        int idx = base + j;
        if (idx < NN) row_start[idx] = excl + v[j];
    }
    if (t == 255) blk_sums[blockIdx.x] = sh[255];
}
__global__ void k_scan_b(const int* __restrict__ blk_sums, int* __restrict__ blk_off) {
    int l = threadIdx.x;  // 64 threads
    int v = (l < NB_SCAN) ? blk_sums[l] : 0;
    int inc = v;
#pragma unroll
    for (int d = 1; d < 64; d <<= 1) {
        int o = __shfl_up(inc, d, 64);
        if (l >= d) inc += o;
    }
    if (l < NB_SCAN) blk_off[l] = inc - v;
}
__global__ void k_scan_c(int* __restrict__ row_start, const int* __restrict__ blk_off,
                         int* __restrict__ pos) {
    int i = blockIdx.x * 256 + threadIdx.x;
    if (i < NN) {
        int r = row_start[i] + blk_off[i >> 11];
        row_start[i] = r;
        pos[i] = r;
        if (i == 0) row_start[NN] = NE;
    }
}
__global__ void k_scatter(const int* __restrict__ srcs, const int* __restrict__ dsts,
                          int* __restrict__ pos, int* __restrict__ src_sorted) {
    int e = blockIdx.x * 256 + threadIdx.x;
    if (e < NE) {
        int p = atomicAdd(&pos[dsts[e]], 1);
        src_sorted[p] = srcs[e];
    }
}

// ---------- conversions ----------
__global__ void k_cvt_x(const float* __restrict__ x, u16* __restrict__ xb) {
    int i = (blockIdx.x * 256 + threadIdx.x) * 4;
    if (i < NN * FIN) {
        float4 f = *(const float4*)(x + i);
        ushort4 o = {f2bf(f.x), f2bf(f.y), f2bf(f.z), f2bf(f.w)};
        *(ushort4*)(xb + i) = o;
    }
}
__global__ void k_cvt_w1(const float* __restrict__ W1, u16* __restrict__ W1t) {
    int i = blockIdx.x * 256 + threadIdx.x;  // [128][96] from [96][128]
    if (i < FH * FIN) {
        int n = i / FIN, k = i % FIN;
        W1t[i] = f2bf(W1[k * FH + n]);
    }
}
__global__ void k_cvt_w2(const float* __restrict__ W2, u16* __restrict__ W2t) {
    int i = blockIdx.x * 256 + threadIdx.x;  // [64][128] from [128][64]
    if (i < FC * FH) {
        int n = i / FH, k = i % FH;
        W2t[i] = f2bf(W2[k * FC + n]);
    }
}

// ---------- aggregation (CSR, no atomics) ----------
__global__ void k_agg1(const u16* __restrict__ xb, const float* __restrict__ dinv,
                       const int* __restrict__ row_start, const int* __restrict__ src_sorted,
                       u16* __restrict__ aggx) {
    int tid = blockIdx.x * 256 + threadIdx.x;
    int dst = tid / 12, q = tid % 12;  // 12 chunks of 8 bf16 = 96 feats
    if (dst >= NN) return;
    int rs = row_start[dst], re = row_start[dst + 1];
    float dv = dinv[dst];
    float acc[8], v[8];
    load8f(xb + (size_t)dst * FIN + q * 8, acc);
#pragma unroll
    for (int j = 0; j < 8; j++) acc[j] *= dv;  // self-loop term
    for (int e = rs; e < re; e++) {
        int s = src_sorted[e];
        float ds_ = dinv[s];
        load8f(xb + (size_t)s * FIN + q * 8, v);
#pragma unroll
        for (int j = 0; j < 8; j++) acc[j] += v[j] * ds_;
    }
#pragma unroll
    for (int j = 0; j < 8; j++) acc[j] *= dv;
    store8bf(aggx + (size_t)dst * FIN + q * 8, acc);
}

__global__ void k_agg2(const u16* __restrict__ zb, const float* __restrict__ dinv,
                       const int* __restrict__ row_start, const int* __restrict__ src_sorted,
                       const float* __restrict__ b2, float* __restrict__ logits) {
    int tid = blockIdx.x * 256 + threadIdx.x;
    int dst = tid / 8, q = tid % 8;  // 8 chunks of 8 = 64 feats
    if (dst >= NN) return;
    int rs = row_start[dst], re = row_start[dst + 1];
    float dv = dinv[dst];
    float acc[8], v[8];
    load8f(zb + (size_t)dst * FC + q * 8, acc);
#pragma unroll
    for (int j = 0; j < 8; j++) acc[j] *= dv;
    for (int e = rs; e < re; e++) {
        int s = src_sorted[e];
        float ds_ = dinv[s];
        load8f(zb + (size_t)s * FC + q * 8, v);
#pragma unroll
        for (int j = 0; j < 8; j++) acc[j] += v[j] * ds_;
    }
    float r[8];
#pragma unroll
    for (int j = 0; j < 8; j++) r[j] = acc[j] * dv + b2[q * 8 + j];
    float4 o0 = {r[0], r[1], r[2], r[3]}, o1 = {r[4], r[5], r[6], r[7]};
    *(float4*)(logits + (size_t)dst * FC + q * 8) = o0;
    *(float4*)(logits + (size_t)dst * FC + q * 8 + 4) = o1;
}

// ---------- GEMM1: h = relu(aggx @ W1 + b1), dual write fp32 + bf16 ----------
__global__ __launch_bounds__(256) void k_gemm1(const u16* __restrict__ aggx,
                                               const u16* __restrict__ W1t,
                                               const float* __restrict__ b1,
                                               float* __restrict__ h, u16* __restrict__ hb) {
    int wave = blockIdx.x * 4 + (threadIdx.x >> 6);
    int row0 = wave << 4;
    if (row0 >= NN) return;
    int lane = threadIdx.x & 63;
    int m = lane & 15, quad = lane >> 4;
    f32x4 acc[8] = {{0,0,0,0},{0,0,0,0},{0,0,0,0},{0,0,0,0},
                    {0,0,0,0},{0,0,0,0},{0,0,0,0},{0,0,0,0}};
#pragma unroll
    for (int kt = 0; kt < 3; kt++) {
        bf16x8 a = *(const bf16x8*)(const void*)(aggx + (size_t)(row0 + m) * FIN + kt * 32 + quad * 8);
#pragma unroll
        for (int nt = 0; nt < 8; nt++) {
            bf16x8 b = *(const bf16x8*)(const void*)(W1t + (size_t)(nt * 16 + m) * FIN + kt * 32 + quad * 8);
            acc[nt] = __builtin_amdgcn_mfma_f32_16x16x32_bf16(a, b, acc[nt], 0, 0, 0);
        }
    }
#pragma unroll
    for (int nt = 0; nt < 8; nt++) {
        int c = nt * 16 + m;
        float bias = b1[c];
#pragma unroll
        for (int i = 0; i < 4; i++) {
            int r = row0 + quad * 4 + i;
            float val = acc[nt][i] + bias;
            val = val > 0.0f ? val : 0.0f;
            h[(size_t)r * FH + c] = val;
            hb[(size_t)r * FH + c] = f2bf(val);
        }
    }
}

// ---------- GEMM2: z = hb @ W2 (bf16 out, no bias) ----------
__global__ __launch_bounds__(256) void k_gemm2(const u16* __restrict__ hb,
                                               const u16* __restrict__ W2t,
                                               u16* __restrict__ zb) {
    int wave = blockIdx.x * 4 + (threadIdx.x >> 6);
    int row0 = wave << 4;
    if (row0 >= NN) return;
    int lane = threadIdx.x & 63;
    int m = lane & 15, quad = lane >> 4;
    f32x4 acc[4] = {{0,0,0,0},{0,0,0,0},{0,0,0,0},{0,0,0,0}};
#pragma unroll
    for (int kt = 0; kt < 4; kt++) {
        bf16x8 a = *(const bf16x8*)(const void*)(hb + (size_t)(row0 + m) * FH + kt * 32 + quad * 8);
#pragma unroll
        for (int nt = 0; nt < 4; nt++) {
            bf16x8 b = *(const bf16x8*)(const void*)(W2t + (size_t)(nt * 16 + m) * FH + kt * 32 + quad * 8);
            acc[nt] = __builtin_amdgcn_mfma_f32_16x16x32_bf16(a, b, acc[nt], 0, 0, 0);
        }
    }
#pragma unroll
    for (int nt = 0; nt < 4; nt++) {
        int c = nt * 16 + m;
#pragma unroll
        for (int i = 0; i < 4; i++) {
            int r = row0 + quad * 4 + i;
            zb[(size_t)r * FC + c] = f2bf(acc[nt][i]);
        }
    }
}

// ---------- log_softmax over 64 cols, in place ----------
__global__ void k_lsm(float* __restrict__ logits) {
    int row = blockIdx.x * 4 + (threadIdx.x >> 6);
    if (row >= NN) return;
    int lane = threadIdx.x & 63;
    float v = logits[(size_t)row * FC + lane];
    float mx = v;
#pragma unroll
    for (int d = 32; d; d >>= 1) mx = fmaxf(mx, __shfl_xor(mx, d, 64));
    float e = expf(v - mx);
    float s = e;
#pragma unroll
    for (int d = 32; d; d >>= 1) s += __shfl_xor(s, d, 64);
    logits[(size_t)row * FC + lane] = v - mx - logf(s);
}

extern "C" void kernel_launch(void* const* d_in, const int* in_sizes, int n_in,
                              void* d_out, int out_size, void* d_ws, size_t ws_size,
                              hipStream_t stream) {
    const float* x  = (const float*)d_in[0];
    const float* W1 = (const float*)d_in[1];
    const float* b1 = (const float*)d_in[2];
    const float* W2 = (const float*)d_in[3];
    const float* b2 = (const float*)d_in[4];
    const int* ei   = (const int*)d_in[5];
    const int* srcs = ei;
    const int* dsts = ei + NE;

    float* logits = (float*)d_out;                    // [N,64]
    float* emb    = (float*)d_out + (size_t)NN * FC;  // [N,128] fp32

    char* w = (char*)d_ws;
    int*   cnt        = (int*)w;   w += 400000;
    float* dinv       = (float*)w; w += 400000;
    int*   row_start  = (int*)w;   w += 400128;  // N+1 ints, padded
    int*   pos        = (int*)w;   w += 400000;
    int*   blk_sums   = (int*)w;   w += 256;
    int*   blk_off    = (int*)w;   w += 256;
    int*   src_sorted = (int*)w;   w += 3200000;
    u16*   xb         = (u16*)w;   w += 19200000;
    u16*   aggx       = (u16*)w;   w += 19200000;
    u16*   W1t        = (u16*)w;   w += 24576;
    u16*   W2t        = (u16*)w;   w += 16384;
    u16*   hb         = (u16*)w;   w += 25600000;
    u16*   zb         = (u16*)w;   w += 12800000;

    hipMemsetAsync(cnt, 0, 400000, stream);
    k_hist<<<(NE + 255) / 256, 256, 0, stream>>>(dsts, cnt);
    k_dinv<<<(NN + 255) / 256, 256, 0, stream>>>(cnt, dinv);
    k_scan_a<<<NB_SCAN, 256, 0, stream>>>(cnt, row_start, blk_sums);
    k_scan_b<<<1, 64, 0, stream>>>(blk_sums, blk_off);
    k_scan_c<<<(NN + 255) / 256, 256, 0, stream>>>(row_start, blk_off, pos);
    k_scatter<<<(NE + 255) / 256, 256, 0, stream>>>(srcs, dsts, pos, src_sorted);
    k_cvt_x<<<(NN * FIN / 4 + 255) / 256, 256, 0, stream>>>(x, xb);
    k_cvt_w1<<<(FH * FIN + 255) / 256, 256, 0, stream>>>(W1, W1t);
    k_cvt_w2<<<(FC * FH + 255) / 256, 256, 0, stream>>>(W2, W2t);
    k_agg1<<<(NN * 12 + 255) / 256, 256, 0, stream>>>(xb, dinv, row_start, src_sorted, aggx);
    k_gemm1<<<(NN / 16 + 3) / 4, 256, 0, stream>>>(aggx, W1t, b1, emb, hb);
    k_gemm2<<<(NN / 16 + 3) / 4, 256, 0, stream>>>(hb, W2t, zb);
    k_agg2<<<(NN * 8 + 255) / 256, 256, 0, stream>>>(zb, dinv, row_start, src_sorted, b2, logits);
    k_lsm<<<(NN + 3) / 4, 256, 0, stream>>>(logits);
}

// Round 2
// 266.569 us; speedup vs baseline: 1.2309x; 1.2309x over previous
//
#include <hip/hip_runtime.h>
#include <hip/hip_bf16.h>

#define NN 100000
#define NE 800000
#define FIN 96
#define FH 128
#define FC 64

#define BLOW 9            // 512 dsts per bucket
#define NBK 196           // ceil(NN/512)
#define BCAP 5120         // bucket capacity (avg 4096, sd ~64)
#define P1E 4096          // edges per k_bin block

typedef unsigned short u16;
typedef unsigned int u32;
typedef __attribute__((ext_vector_type(8))) __bf16 bf16x8;
typedef __attribute__((ext_vector_type(4))) float f32x4;

__device__ __forceinline__ float bf2f(u16 u) {
    u32 x = ((u32)u) << 16;
    return __builtin_bit_cast(float, x);
}
__device__ __forceinline__ u16 f2bf(float f) {
    u32 u = __builtin_bit_cast(u32, f);
    u += 0x7fffu + ((u >> 16) & 1u);
    return (u16)(u >> 16);
}
__device__ __forceinline__ void load8f(const u16* p, float* o) {
    uint4 pk = *(const uint4*)p;
    o[0] = bf2f((u16)pk.x); o[1] = bf2f((u16)(pk.x >> 16));
    o[2] = bf2f((u16)pk.y); o[3] = bf2f((u16)(pk.y >> 16));
    o[4] = bf2f((u16)pk.z); o[5] = bf2f((u16)(pk.z >> 16));
    o[6] = bf2f((u16)pk.w); o[7] = bf2f((u16)(pk.w >> 16));
}
__device__ __forceinline__ void store8bf(u16* p, const float* v) {
    uint4 pk;
    pk.x = (u32)f2bf(v[0]) | ((u32)f2bf(v[1]) << 16);
    pk.y = (u32)f2bf(v[2]) | ((u32)f2bf(v[3]) << 16);
    pk.z = (u32)f2bf(v[4]) | ((u32)f2bf(v[5]) << 16);
    pk.w = (u32)f2bf(v[6]) | ((u32)f2bf(v[7]) << 16);
    *(uint4*)p = pk;
}

// ---------- phase 1: bin edges by dst bucket, LDS-grouped coalesced output ----------
__global__ __launch_bounds__(256) void k_bin(const int* __restrict__ srcs,
                                             const int* __restrict__ dsts,
                                             int* __restrict__ bucket_cursor,
                                             u32* __restrict__ bucket_data) {
    __shared__ int s_hist[256];
    __shared__ int s_base[256];
    __shared__ int s_cur[256];
    __shared__ int s_gbase[256];
    __shared__ u32 s_sorted[P1E];
    __shared__ unsigned char s_bkt[P1E];
    int t = threadIdx.x;
    int e0 = blockIdx.x * P1E;
    int n = NE - e0; if (n > P1E) n = P1E;
    s_hist[t] = 0;
    __syncthreads();
    u32 rp[16]; int rb[16];
#pragma unroll
    for (int j = 0; j < 16; j++) {
        int i = j * 256 + t;
        rb[j] = -1;
        if (i < n) {
            int s = srcs[e0 + i], d = dsts[e0 + i];
            int b = d >> BLOW;
            rb[j] = b;
            rp[j] = ((u32)(d & ((1 << BLOW) - 1)) << 17) | (u32)s;
            atomicAdd(&s_hist[b], 1);
        }
    }
    __syncthreads();
    int ct = s_hist[t];
    s_base[t] = ct;
    __syncthreads();
    for (int off = 1; off < 256; off <<= 1) {
        int v = (t >= off) ? s_base[t - off] : 0;
        __syncthreads();
        s_base[t] += v;
        __syncthreads();
    }
    int excl = s_base[t] - ct;
    __syncthreads();
    s_base[t] = excl;
    s_cur[t] = excl;
    if (t < NBK) s_gbase[t] = (ct > 0) ? atomicAdd(&bucket_cursor[t], ct) : 0;
    __syncthreads();
#pragma unroll
    for (int j = 0; j < 16; j++) {
        if (rb[j] >= 0) {
            int r = atomicAdd(&s_cur[rb[j]], 1);
            s_sorted[r] = rp[j];
            s_bkt[r] = (unsigned char)rb[j];
        }
    }
    __syncthreads();
    for (int i = t; i < n; i += 256) {
        int b = s_bkt[i];
        int gpos = s_gbase[b] + (i - s_base[b]);
        if (gpos < BCAP)
            bucket_data[(size_t)b * BCAP + gpos] = s_sorted[i];
    }
}

// ---------- phase 2: per-bucket counting sort -> CSR + row_start + dinv ----------
__global__ __launch_bounds__(256) void k_csr(const int* __restrict__ bucket_cursor,
                                             const u32* __restrict__ bucket_data,
                                             int* __restrict__ row_start,
                                             float* __restrict__ dinv,
                                             int* __restrict__ src_sorted) {
    __shared__ int s_c[256];
    __shared__ int s_cnt[512];
    __shared__ int s_ps[256];
    __shared__ int s_off[512];
    __shared__ int s_cur[512];
    __shared__ u32 s_edges[BCAP];
    int t = threadIdx.x;
    int b = blockIdx.x;
    int nbe = bucket_cursor[b];
    if (nbe > BCAP) nbe = BCAP;
    // exclusive scan over all bucket sizes -> this bucket's base in CSR
    s_c[t] = (t < NBK) ? bucket_cursor[t] : 0;
    __syncthreads();
    for (int off = 1; off < 256; off <<= 1) {
        int v = (t >= off) ? s_c[t - off] : 0;
        __syncthreads();
        s_c[t] += v;
        __syncthreads();
    }
    int bbase = s_c[b] - nbe;
    // stage + histogram
    s_cnt[t] = 0; s_cnt[t + 256] = 0;
    __syncthreads();
    for (int i = t; i < nbe; i += 256) {
        u32 p = bucket_data[(size_t)b * BCAP + i];
        s_edges[i] = p;
        atomicAdd(&s_cnt[p >> 17], 1);
    }
    __syncthreads();
    // exclusive scan of 512 counts (pairwise + 256-scan)
    int c0 = s_cnt[2 * t], c1 = s_cnt[2 * t + 1];
    s_ps[t] = c0 + c1;
    __syncthreads();
    for (int off = 1; off < 256; off <<= 1) {
        int v = (t >= off) ? s_ps[t - off] : 0;
        __syncthreads();
        s_ps[t] += v;
        __syncthreads();
    }
    int pexcl = s_ps[t] - (c0 + c1);
    s_off[2 * t] = pexcl;      s_cur[2 * t] = pexcl;
    s_off[2 * t + 1] = pexcl + c0; s_cur[2 * t + 1] = pexcl + c0;
    __syncthreads();
    // row_start + dinv (coalesced)
#pragma unroll
    for (int k = 0; k < 2; k++) {
        int ld = k * 256 + t;
        int gd = b * 512 + ld;
        if (gd < NN) {
            row_start[gd] = bbase + s_off[ld];
            dinv[gd] = rsqrtf((float)s_cnt[ld] + 1.0f);
        }
    }
    if (b == 0 && t == 0) row_start[NN] = NE;
    // scatter within L2-resident region
    for (int i = t; i < nbe; i += 256) {
        u32 p = s_edges[i];
        int d = p >> 17;
        int r = atomicAdd(&s_cur[d], 1);
        src_sorted[bbase + r] = (int)(p & 0x1FFFFu);
    }
}

// ---------- conversions ----------
__global__ void k_cvt_x(const float* __restrict__ x, u16* __restrict__ xb) {
    int i = (blockIdx.x * 256 + threadIdx.x) * 4;
    if (i < NN * FIN) {
        float4 f = *(const float4*)(x + i);
        ushort4 o = {f2bf(f.x), f2bf(f.y), f2bf(f.z), f2bf(f.w)};
        *(ushort4*)(xb + i) = o;
    }
}
__global__ void k_cvt_w1(const float* __restrict__ W1, u16* __restrict__ W1t) {
    int i = blockIdx.x * 256 + threadIdx.x;  // [128][96] from [96][128]
    if (i < FH * FIN) {
        int n = i / FIN, k = i % FIN;
        W1t[i] = f2bf(W1[k * FH + n]);
    }
}
__global__ void k_cvt_w2(const float* __restrict__ W2, u16* __restrict__ W2t) {
    int i = blockIdx.x * 256 + threadIdx.x;  // [64][128] from [128][64]
    if (i < FC * FH) {
        int n = i / FH, k = i % FH;
        W2t[i] = f2bf(W2[k * FC + n]);
    }
}

// ---------- aggregation (CSR, no atomics) ----------
__global__ void k_agg1(const u16* __restrict__ xb, const float* __restrict__ dinv,
                       const int* __restrict__ row_start, const int* __restrict__ src_sorted,
                       u16* __restrict__ aggx) {
    int tid = blockIdx.x * 256 + threadIdx.x;
    int dst = tid / 12, q = tid % 12;  // 12 chunks of 8 bf16 = 96 feats
    if (dst >= NN) return;
    int rs = row_start[dst], re = row_start[dst + 1];
    float dv = dinv[dst];
    float acc[8], v[8];
    load8f(xb + (size_t)dst * FIN + q * 8, acc);
#pragma unroll
    for (int j = 0; j < 8; j++) acc[j] *= dv;  // self-loop term
    for (int e = rs; e < re; e++) {
        int s = src_sorted[e];
        float ds_ = dinv[s];
        load8f(xb + (size_t)s * FIN + q * 8, v);
#pragma unroll
        for (int j = 0; j < 8; j++) acc[j] += v[j] * ds_;
    }
#pragma unroll
    for (int j = 0; j < 8; j++) acc[j] *= dv;
    store8bf(aggx + (size_t)dst * FIN + q * 8, acc);
}

__global__ void k_agg2(const u16* __restrict__ zb, const float* __restrict__ dinv,
                       const int* __restrict__ row_start, const int* __restrict__ src_sorted,
                       const float* __restrict__ b2, float* __restrict__ logits) {
    int tid = blockIdx.x * 256 + threadIdx.x;
    int dst = tid / 8, q = tid % 8;  // 8 chunks of 8 = 64 feats
    if (dst >= NN) return;
    int rs = row_start[dst], re = row_start[dst + 1];
    float dv = dinv[dst];
    float acc[8], v[8];
    load8f(zb + (size_t)dst * FC + q * 8, acc);
#pragma unroll
    for (int j = 0; j < 8; j++) acc[j] *= dv;
    for (int e = rs; e < re; e++) {
        int s = src_sorted[e];
        float ds_ = dinv[s];
        load8f(zb + (size_t)s * FC + q * 8, v);
#pragma unroll
        for (int j = 0; j < 8; j++) acc[j] += v[j] * ds_;
    }
    float r[8];
#pragma unroll
    for (int j = 0; j < 8; j++) r[j] = acc[j] * dv + b2[q * 8 + j];
    float4 o0 = {r[0], r[1], r[2], r[3]}, o1 = {r[4], r[5], r[6], r[7]};
    *(float4*)(logits + (size_t)dst * FC + q * 8) = o0;
    *(float4*)(logits + (size_t)dst * FC + q * 8 + 4) = o1;
}

// ---------- GEMM1: h = relu(aggx @ W1 + b1), dual write fp32 + bf16 ----------
__global__ __launch_bounds__(256) void k_gemm1(const u16* __restrict__ aggx,
                                               const u16* __restrict__ W1t,
                                               const float* __restrict__ b1,
                                               float* __restrict__ h, u16* __restrict__ hb) {
    int wave = blockIdx.x * 4 + (threadIdx.x >> 6);
    int row0 = wave << 4;
    if (row0 >= NN) return;
    int lane = threadIdx.x & 63;
    int m = lane & 15, quad = lane >> 4;
    f32x4 acc[8] = {{0,0,0,0},{0,0,0,0},{0,0,0,0},{0,0,0,0},
                    {0,0,0,0},{0,0,0,0},{0,0,0,0},{0,0,0,0}};
#pragma unroll
    for (int kt = 0; kt < 3; kt++) {
        bf16x8 a = *(const bf16x8*)(const void*)(aggx + (size_t)(row0 + m) * FIN + kt * 32 + quad * 8);
#pragma unroll
        for (int nt = 0; nt < 8; nt++) {
            bf16x8 b = *(const bf16x8*)(const void*)(W1t + (size_t)(nt * 16 + m) * FIN + kt * 32 + quad * 8);
            acc[nt] = __builtin_amdgcn_mfma_f32_16x16x32_bf16(a, b, acc[nt], 0, 0, 0);
        }
    }
#pragma unroll
    for (int nt = 0; nt < 8; nt++) {
        int c = nt * 16 + m;
        float bias = b1[c];
#pragma unroll
        for (int i = 0; i < 4; i++) {
            int r = row0 + quad * 4 + i;
            float val = acc[nt][i] + bias;
            val = val > 0.0f ? val : 0.0f;
            h[(size_t)r * FH + c] = val;
            hb[(size_t)r * FH + c] = f2bf(val);
        }
    }
}

// ---------- GEMM2: z = hb @ W2 (bf16 out, no bias) ----------
__global__ __launch_bounds__(256) void k_gemm2(const u16* __restrict__ hb,
                                               const u16* __restrict__ W2t,
                                               u16* __restrict__ zb) {
    int wave = blockIdx.x * 4 + (threadIdx.x >> 6);
    int row0 = wave << 4;
    if (row0 >= NN) return;
    int lane = threadIdx.x & 63;
    int m = lane & 15, quad = lane >> 4;
    f32x4 acc[4] = {{0,0,0,0},{0,0,0,0},{0,0,0,0},{0,0,0,0}};
#pragma unroll
    for (int kt = 0; kt < 4; kt++) {
        bf16x8 a = *(const bf16x8*)(const void*)(hb + (size_t)(row0 + m) * FH + kt * 32 + quad * 8);
#pragma unroll
        for (int nt = 0; nt < 4; nt++) {
            bf16x8 b = *(const bf16x8*)(const void*)(W2t + (size_t)(nt * 16 + m) * FH + kt * 32 + quad * 8);
            acc[nt] = __builtin_amdgcn_mfma_f32_16x16x32_bf16(a, b, acc[nt], 0, 0, 0);
        }
    }
#pragma unroll
    for (int nt = 0; nt < 4; nt++) {
        int c = nt * 16 + m;
#pragma unroll
        for (int i = 0; i < 4; i++) {
            int r = row0 + quad * 4 + i;
            zb[(size_t)r * FC + c] = f2bf(acc[nt][i]);
        }
    }
}

// ---------- log_softmax over 64 cols, in place ----------
__global__ void k_lsm(float* __restrict__ logits) {
    int row = blockIdx.x * 4 + (threadIdx.x >> 6);
    if (row >= NN) return;
    int lane = threadIdx.x & 63;
    float v = logits[(size_t)row * FC + lane];
    float mx = v;
#pragma unroll
    for (int d = 32; d; d >>= 1) mx = fmaxf(mx, __shfl_xor(mx, d, 64));
    float e = expf(v - mx);
    float s = e;
#pragma unroll
    for (int d = 32; d; d >>= 1) s += __shfl_xor(s, d, 64);
    logits[(size_t)row * FC + lane] = v - mx - logf(s);
}

extern "C" void kernel_launch(void* const* d_in, const int* in_sizes, int n_in,
                              void* d_out, int out_size, void* d_ws, size_t ws_size,
                              hipStream_t stream) {
    const float* x  = (const float*)d_in[0];
    const float* W1 = (const float*)d_in[1];
    const float* b1 = (const float*)d_in[2];
    const float* W2 = (const float*)d_in[3];
    const float* b2 = (const float*)d_in[4];
    const int* ei   = (const int*)d_in[5];
    const int* srcs = ei;
    const int* dsts = ei + NE;

    float* logits = (float*)d_out;                    // [N,64]
    float* emb    = (float*)d_out + (size_t)NN * FC;  // [N,128] fp32

    char* w = (char*)d_ws;
    float* dinv       = (float*)w; w += 400000;
    int*   row_start  = (int*)w;   w += 400128;  // N+1 ints, padded
    int*   src_sorted = (int*)w;   w += 3200000;
    int*   bucket_cursor = (int*)w; w += 1024;
    u16*   xb         = (u16*)w;   w += 19200000;
    u16*   aggx       = (u16*)w;   w += 19200000;
    u16*   W1t        = (u16*)w;   w += 24576;
    u16*   W2t        = (u16*)w;   w += 16384;
    u16*   hb         = (u16*)w;   w += 25600000;
    u16*   zb         = (u16*)w;   w += 12800000;
    // bucket_data overlays aggx (dead before k_agg1 writes aggx)
    u32*   bucket_data = (u32*)aggx;

    hipMemsetAsync(bucket_cursor, 0, NBK * 4, stream);
    k_bin<<<(NE + P1E - 1) / P1E, 256, 0, stream>>>(srcs, dsts, bucket_cursor, bucket_data);
    k_csr<<<NBK, 256, 0, stream>>>(bucket_cursor, bucket_data, row_start, dinv, src_sorted);
    k_cvt_x<<<(NN * FIN / 4 + 255) / 256, 256, 0, stream>>>(x, xb);
    k_cvt_w1<<<(FH * FIN + 255) / 256, 256, 0, stream>>>(W1, W1t);
    k_cvt_w2<<<(FC * FH + 255) / 256, 256, 0, stream>>>(W2, W2t);
    k_agg1<<<(NN * 12 + 255) / 256, 256, 0, stream>>>(xb, dinv, row_start, src_sorted, aggx);
    k_gemm1<<<(NN / 16 + 3) / 4, 256, 0, stream>>>(aggx, W1t, b1, emb, hb);
    k_gemm2<<<(NN / 16 + 3) / 4, 256, 0, stream>>>(hb, W2t, zb);
    k_agg2<<<(NN * 8 + 255) / 256, 256, 0, stream>>>(zb, dinv, row_start, src_sorted, b2, logits);
    k_lsm<<<(NN + 3) / 4, 256, 0, stream>>>(logits);
}

// Round 3
// 262.693 us; speedup vs baseline: 1.2491x; 1.0148x over previous
//
#include <hip/hip_runtime.h>
#include <hip/hip_bf16.h>

#define NN 100000
#define NE 800000
#define FIN 96
#define FH 128
#define FC 64

#define BLOW 9            // 512 dsts per bucket
#define NBK 196           // ceil(NN/512)
#define BCAP 5120         // bucket capacity (avg 4096, sd ~64)
#define P1E 4096          // edges per k_bin block

typedef unsigned short u16;
typedef unsigned int u32;
typedef __attribute__((ext_vector_type(8))) __bf16 bf16x8;
typedef __attribute__((ext_vector_type(4))) float f32x4;

__device__ __forceinline__ float bf2f(u16 u) {
    u32 x = ((u32)u) << 16;
    return __builtin_bit_cast(float, x);
}
__device__ __forceinline__ u16 f2bf(float f) {
    u32 u = __builtin_bit_cast(u32, f);
    u += 0x7fffu + ((u >> 16) & 1u);
    return (u16)(u >> 16);
}
__device__ __forceinline__ void load8f(const u16* p, float* o) {
    uint4 pk = *(const uint4*)p;
    o[0] = bf2f((u16)pk.x); o[1] = bf2f((u16)(pk.x >> 16));
    o[2] = bf2f((u16)pk.y); o[3] = bf2f((u16)(pk.y >> 16));
    o[4] = bf2f((u16)pk.z); o[5] = bf2f((u16)(pk.z >> 16));
    o[6] = bf2f((u16)pk.w); o[7] = bf2f((u16)(pk.w >> 16));
}
__device__ __forceinline__ void store8bf(u16* p, const float* v) {
    uint4 pk;
    pk.x = (u32)f2bf(v[0]) | ((u32)f2bf(v[1]) << 16);
    pk.y = (u32)f2bf(v[2]) | ((u32)f2bf(v[3]) << 16);
    pk.z = (u32)f2bf(v[4]) | ((u32)f2bf(v[5]) << 16);
    pk.w = (u32)f2bf(v[6]) | ((u32)f2bf(v[7]) << 16);
    *(uint4*)p = pk;
}

// ---------- phase 1: bin edges by dst bucket, LDS-grouped coalesced output ----------
__global__ __launch_bounds__(256) void k_bin(const int* __restrict__ srcs,
                                             const int* __restrict__ dsts,
                                             int* __restrict__ bucket_cursor,
                                             u32* __restrict__ bucket_data) {
    __shared__ int s_hist[256];
    __shared__ int s_base[256];
    __shared__ int s_cur[256];
    __shared__ int s_gbase[256];
    __shared__ u32 s_sorted[P1E];
    __shared__ unsigned char s_bkt[P1E];
    int t = threadIdx.x;
    int e0 = blockIdx.x * P1E;
    int n = NE - e0; if (n > P1E) n = P1E;
    s_hist[t] = 0;
    __syncthreads();
    u32 rp[16]; int rb[16];
#pragma unroll
    for (int j = 0; j < 16; j++) {
        int i = j * 256 + t;
        rb[j] = -1;
        if (i < n) {
            int s = srcs[e0 + i], d = dsts[e0 + i];
            int b = d >> BLOW;
            rb[j] = b;
            rp[j] = ((u32)(d & ((1 << BLOW) - 1)) << 17) | (u32)s;
            atomicAdd(&s_hist[b], 1);
        }
    }
    __syncthreads();
    int ct = s_hist[t];
    s_base[t] = ct;
    __syncthreads();
    for (int off = 1; off < 256; off <<= 1) {
        int v = (t >= off) ? s_base[t - off] : 0;
        __syncthreads();
        s_base[t] += v;
        __syncthreads();
    }
    int excl = s_base[t] - ct;
    __syncthreads();
    s_base[t] = excl;
    s_cur[t] = excl;
    if (t < NBK) s_gbase[t] = (ct > 0) ? atomicAdd(&bucket_cursor[t], ct) : 0;
    __syncthreads();
#pragma unroll
    for (int j = 0; j < 16; j++) {
        if (rb[j] >= 0) {
            int r = atomicAdd(&s_cur[rb[j]], 1);
            s_sorted[r] = rp[j];
            s_bkt[r] = (unsigned char)rb[j];
        }
    }
    __syncthreads();
    for (int i = t; i < n; i += 256) {
        int b = s_bkt[i];
        int gpos = s_gbase[b] + (i - s_base[b]);
        if (gpos < BCAP)
            bucket_data[(size_t)b * BCAP + gpos] = s_sorted[i];
    }
}

// ---------- phase 2: per-bucket counting sort -> CSR + row_start + dinv ----------
__global__ __launch_bounds__(256) void k_csr(const int* __restrict__ bucket_cursor,
                                             const u32* __restrict__ bucket_data,
                                             int* __restrict__ row_start,
                                             float* __restrict__ dinv,
                                             int* __restrict__ src_sorted) {
    __shared__ int s_c[256];
    __shared__ int s_cnt[512];
    __shared__ int s_ps[256];
    __shared__ int s_off[512];
    __shared__ int s_cur[512];
    __shared__ u32 s_edges[BCAP];
    int t = threadIdx.x;
    int b = blockIdx.x;
    int nbe = bucket_cursor[b];
    if (nbe > BCAP) nbe = BCAP;
    s_c[t] = (t < NBK) ? bucket_cursor[t] : 0;
    __syncthreads();
    for (int off = 1; off < 256; off <<= 1) {
        int v = (t >= off) ? s_c[t - off] : 0;
        __syncthreads();
        s_c[t] += v;
        __syncthreads();
    }
    int bbase = s_c[b] - nbe;
    s_cnt[t] = 0; s_cnt[t + 256] = 0;
    __syncthreads();
    for (int i = t; i < nbe; i += 256) {
        u32 p = bucket_data[(size_t)b * BCAP + i];
        s_edges[i] = p;
        atomicAdd(&s_cnt[p >> 17], 1);
    }
    __syncthreads();
    int c0 = s_cnt[2 * t], c1 = s_cnt[2 * t + 1];
    s_ps[t] = c0 + c1;
    __syncthreads();
    for (int off = 1; off < 256; off <<= 1) {
        int v = (t >= off) ? s_ps[t - off] : 0;
        __syncthreads();
        s_ps[t] += v;
        __syncthreads();
    }
    int pexcl = s_ps[t] - (c0 + c1);
    s_off[2 * t] = pexcl;          s_cur[2 * t] = pexcl;
    s_off[2 * t + 1] = pexcl + c0; s_cur[2 * t + 1] = pexcl + c0;
    __syncthreads();
#pragma unroll
    for (int k = 0; k < 2; k++) {
        int ld = k * 256 + t;
        int gd = b * 512 + ld;
        if (gd < NN) {
            row_start[gd] = bbase + s_off[ld];
            dinv[gd] = rsqrtf((float)s_cnt[ld] + 1.0f);
        }
    }
    if (b == 0 && t == 0) row_start[NN] = NE;
    for (int i = t; i < nbe; i += 256) {
        u32 p = s_edges[i];
        int d = p >> 17;
        int r = atomicAdd(&s_cur[d], 1);
        src_sorted[bbase + r] = (int)(p & 0x1FFFFu);
    }
}

// ---------- conversions ----------
__global__ void k_cvt_x(const float* __restrict__ x, u16* __restrict__ xb) {
    int i = (blockIdx.x * 256 + threadIdx.x) * 4;
    if (i < NN * FIN) {
        float4 f = *(const float4*)(x + i);
        ushort4 o = {f2bf(f.x), f2bf(f.y), f2bf(f.z), f2bf(f.w)};
        *(ushort4*)(xb + i) = o;
    }
}
__global__ void k_cvt_w(const float* __restrict__ W1, const float* __restrict__ W2,
                        u16* __restrict__ W1t, u16* __restrict__ W2t) {
    int i = blockIdx.x * 256 + threadIdx.x;
    if (i < FH * FIN) {                       // W1t[128][96] from W1[96][128]
        int n = i / FIN, k = i % FIN;
        W1t[i] = f2bf(W1[k * FH + n]);
    } else if (i < FH * FIN + FC * FH) {      // W2t[64][128] from W2[128][64]
        int j = i - FH * FIN;
        int n = j / FH, k = j % FH;
        W2t[j] = f2bf(W2[k * FC + n]);
    }
}

// ---------- aggregation layer 1 (CSR, no atomics, unroll-2) ----------
__global__ void k_agg1(const u16* __restrict__ xb, const float* __restrict__ dinv,
                       const int* __restrict__ row_start, const int* __restrict__ src_sorted,
                       u16* __restrict__ aggx) {
    int tid = blockIdx.x * 256 + threadIdx.x;
    int dst = tid / 12, q = tid % 12;  // 12 chunks of 8 bf16 = 96 feats
    if (dst >= NN) return;
    int rs = row_start[dst], re = row_start[dst + 1];
    float dv = dinv[dst];
    float acc[8], v0[8], v1[8];
    load8f(xb + (size_t)dst * FIN + q * 8, acc);
#pragma unroll
    for (int j = 0; j < 8; j++) acc[j] *= dv;  // self-loop term
    int e = rs;
    for (; e + 1 < re; e += 2) {
        int s0 = src_sorted[e], s1 = src_sorted[e + 1];
        float d0 = dinv[s0], d1 = dinv[s1];
        load8f(xb + (size_t)s0 * FIN + q * 8, v0);
        load8f(xb + (size_t)s1 * FIN + q * 8, v1);
#pragma unroll
        for (int j = 0; j < 8; j++) acc[j] += v0[j] * d0 + v1[j] * d1;
    }
    if (e < re) {
        int s0 = src_sorted[e];
        float d0 = dinv[s0];
        load8f(xb + (size_t)s0 * FIN + q * 8, v0);
#pragma unroll
        for (int j = 0; j < 8; j++) acc[j] += v0[j] * d0;
    }
#pragma unroll
    for (int j = 0; j < 8; j++) acc[j] *= dv;
    store8bf(aggx + (size_t)dst * FIN + q * 8, acc);
}

// ---------- fused GEMM1+GEMM2: emb = relu(aggx@W1+b1) [fp32 out], zb = emb@W2 [bf16] ----------
// 2 waves/block, 3125 blocks -> exactly 6250 waves = NN/16 row-tiles, no early exit.
#define LDSW 136  // 128 + 8 pad (keeps 16B alignment, <=4-way ds_read_b128 conflict)
__global__ __launch_bounds__(128) void k_gemm12(const u16* __restrict__ aggx,
                                                const u16* __restrict__ W1t,
                                                const float* __restrict__ b1,
                                                const u16* __restrict__ W2t,
                                                float* __restrict__ emb,
                                                u16* __restrict__ zb) {
    __shared__ u16 sh[2][16 * LDSW];
    int wid = threadIdx.x >> 6, lane = threadIdx.x & 63;
    int wave = blockIdx.x * 2 + wid;
    int row0 = wave << 4;
    int m = lane & 15, quad = lane >> 4;
    f32x4 acc[8] = {{0,0,0,0},{0,0,0,0},{0,0,0,0},{0,0,0,0},
                    {0,0,0,0},{0,0,0,0},{0,0,0,0},{0,0,0,0}};
#pragma unroll
    for (int kt = 0; kt < 3; kt++) {
        bf16x8 a = *(const bf16x8*)(const void*)(aggx + (size_t)(row0 + m) * FIN + kt * 32 + quad * 8);
#pragma unroll
        for (int nt = 0; nt < 8; nt++) {
            bf16x8 b = *(const bf16x8*)(const void*)(W1t + (size_t)(nt * 16 + m) * FIN + kt * 32 + quad * 8);
            acc[nt] = __builtin_amdgcn_mfma_f32_16x16x32_bf16(a, b, acc[nt], 0, 0, 0);
        }
    }
    u16* tile = sh[wid];
#pragma unroll
    for (int nt = 0; nt < 8; nt++) {
        int c = nt * 16 + m;
        float bias = b1[c];
#pragma unroll
        for (int i = 0; i < 4; i++) {
            int r = quad * 4 + i;
            float val = acc[nt][i] + bias;
            val = val > 0.0f ? val : 0.0f;
            emb[(size_t)(row0 + r) * FH + c] = val;
            tile[r * LDSW + c] = f2bf(val);
        }
    }
    __syncthreads();
    f32x4 zacc[4] = {{0,0,0,0},{0,0,0,0},{0,0,0,0},{0,0,0,0}};
#pragma unroll
    for (int kt = 0; kt < 4; kt++) {
        bf16x8 a = *(const bf16x8*)(const void*)(tile + m * LDSW + kt * 32 + quad * 8);
#pragma unroll
        for (int nt = 0; nt < 4; nt++) {
            bf16x8 b = *(const bf16x8*)(const void*)(W2t + (size_t)(nt * 16 + m) * FH + kt * 32 + quad * 8);
            zacc[nt] = __builtin_amdgcn_mfma_f32_16x16x32_bf16(a, b, zacc[nt], 0, 0, 0);
        }
    }
#pragma unroll
    for (int nt = 0; nt < 4; nt++) {
        int c = nt * 16 + m;
#pragma unroll
        for (int i = 0; i < 4; i++) {
            int r = row0 + quad * 4 + i;
            zb[(size_t)r * FC + c] = f2bf(zacc[nt][i]);
        }
    }
}

// ---------- fused agg layer 2 + bias + log_softmax: wave-per-dst ----------
__global__ void k_agg2lsm(const u16* __restrict__ zb, const float* __restrict__ dinv,
                          const int* __restrict__ row_start, const int* __restrict__ src_sorted,
                          const float* __restrict__ b2, float* __restrict__ logits) {
    int wid = threadIdx.x >> 6, lane = threadIdx.x & 63;
    int dst = blockIdx.x * 4 + wid;
    if (dst >= NN) return;
    int rs = row_start[dst], re = row_start[dst + 1];
    float dv = dinv[dst];
    float acc = bf2f(zb[(size_t)dst * FC + lane]) * dv;
    int e = rs;
    for (; e + 1 < re; e += 2) {
        int s0 = src_sorted[e], s1 = src_sorted[e + 1];
        float d0 = dinv[s0], d1 = dinv[s1];
        float v0 = bf2f(zb[(size_t)s0 * FC + lane]);
        float v1 = bf2f(zb[(size_t)s1 * FC + lane]);
        acc += v0 * d0 + v1 * d1;
    }
    if (e < re) {
        int s0 = src_sorted[e];
        acc += bf2f(zb[(size_t)s0 * FC + lane]) * dinv[s0];
    }
    float v = acc * dv + b2[lane];
    float mx = v;
#pragma unroll
    for (int d = 32; d; d >>= 1) mx = fmaxf(mx, __shfl_xor(mx, d, 64));
    float ex = expf(v - mx);
    float s = ex;
#pragma unroll
    for (int d = 32; d; d >>= 1) s += __shfl_xor(s, d, 64);
    logits[(size_t)dst * FC + lane] = v - mx - logf(s);
}

extern "C" void kernel_launch(void* const* d_in, const int* in_sizes, int n_in,
                              void* d_out, int out_size, void* d_ws, size_t ws_size,
                              hipStream_t stream) {
    const float* x  = (const float*)d_in[0];
    const float* W1 = (const float*)d_in[1];
    const float* b1 = (const float*)d_in[2];
    const float* W2 = (const float*)d_in[3];
    const float* b2 = (const float*)d_in[4];
    const int* ei   = (const int*)d_in[5];
    const int* srcs = ei;
    const int* dsts = ei + NE;

    float* logits = (float*)d_out;                    // [N,64]
    float* emb    = (float*)d_out + (size_t)NN * FC;  // [N,128] fp32

    char* w = (char*)d_ws;
    float* dinv       = (float*)w; w += 400000;
    int*   row_start  = (int*)w;   w += 400128;  // N+1 ints, padded
    int*   src_sorted = (int*)w;   w += 3200000;
    int*   bucket_cursor = (int*)w; w += 1024;
    u16*   xb         = (u16*)w;   w += 19200000;
    u16*   aggx       = (u16*)w;   w += 19200000;
    u16*   W1t        = (u16*)w;   w += 24576;
    u16*   W2t        = (u16*)w;   w += 16384;
    u16*   zb         = (u16*)w;   w += 12800000;
    // bucket_data overlays aggx (dead before k_agg1 writes aggx)
    u32*   bucket_data = (u32*)aggx;

    hipMemsetAsync(bucket_cursor, 0, NBK * 4, stream);
    k_bin<<<(NE + P1E - 1) / P1E, 256, 0, stream>>>(srcs, dsts, bucket_cursor, bucket_data);
    k_csr<<<NBK, 256, 0, stream>>>(bucket_cursor, bucket_data, row_start, dinv, src_sorted);
    k_cvt_x<<<(NN * FIN / 4 + 255) / 256, 256, 0, stream>>>(x, xb);
    k_cvt_w<<<(FH * FIN + FC * FH + 255) / 256, 256, 0, stream>>>(W1, W2, W1t, W2t);
    k_agg1<<<(NN * 12 + 255) / 256, 256, 0, stream>>>(xb, dinv, row_start, src_sorted, aggx);
    k_gemm12<<<NN / 32, 128, 0, stream>>>(aggx, W1t, b1, W2t, emb, zb);
    k_agg2lsm<<<(NN + 3) / 4, 256, 0, stream>>>(zb, dinv, row_start, src_sorted, b2, logits);
}

// Round 4
// 224.684 us; speedup vs baseline: 1.4604x; 1.1692x over previous
//
#include <hip/hip_runtime.h>
#include <hip/hip_bf16.h>

#define NN 100000
#define NE 800000
#define FIN 96
#define FH 128
#define FC 64

#define BLOW 9            // 512 dsts per bucket
#define NBK 196           // ceil(NN/512)
#define BCAP 5120         // bucket capacity (avg 4096, sd ~64)
#define P1E 4096          // edges per bin block
#define NB_CVTX ((NN * FIN / 4 + 255) / 256)   // 9375

typedef unsigned short u16;
typedef unsigned int u32;
typedef __attribute__((ext_vector_type(8))) __bf16 bf16x8;
typedef __attribute__((ext_vector_type(4))) float f32x4;

__device__ __forceinline__ float bf2f(u16 u) {
    u32 x = ((u32)u) << 16;
    return __builtin_bit_cast(float, x);
}
__device__ __forceinline__ u16 f2bf(float f) {
    u32 u = __builtin_bit_cast(u32, f);
    u += 0x7fffu + ((u >> 16) & 1u);
    return (u16)(u >> 16);
}
__device__ __forceinline__ void load8f(const u16* p, float* o) {
    uint4 pk = *(const uint4*)p;
    o[0] = bf2f((u16)pk.x); o[1] = bf2f((u16)(pk.x >> 16));
    o[2] = bf2f((u16)pk.y); o[3] = bf2f((u16)(pk.y >> 16));
    o[4] = bf2f((u16)pk.z); o[5] = bf2f((u16)(pk.z >> 16));
    o[6] = bf2f((u16)pk.w); o[7] = bf2f((u16)(pk.w >> 16));
}
__device__ __forceinline__ void store8bf(u16* p, const float* v) {
    uint4 pk;
    pk.x = (u32)f2bf(v[0]) | ((u32)f2bf(v[1]) << 16);
    pk.y = (u32)f2bf(v[2]) | ((u32)f2bf(v[3]) << 16);
    pk.z = (u32)f2bf(v[4]) | ((u32)f2bf(v[5]) << 16);
    pk.w = (u32)f2bf(v[6]) | ((u32)f2bf(v[7]) << 16);
    *(uint4*)p = pk;
}

// ---------- fused prep: [0,196) bin edges | [196,196+9375) cvt_x | last cvt_w ----------
__global__ __launch_bounds__(256) void k_prep(const int* __restrict__ srcs,
                                              const int* __restrict__ dsts,
                                              int* __restrict__ bucket_cursor,
                                              u32* __restrict__ bucket_data,
                                              const float* __restrict__ x,
                                              u16* __restrict__ xb,
                                              const float* __restrict__ W1,
                                              const float* __restrict__ W2,
                                              u16* __restrict__ W1t,
                                              u16* __restrict__ W2t) {
    __shared__ int s_hist[256];
    __shared__ int s_base[256];
    __shared__ int s_cur[256];
    __shared__ int s_gbase[256];
    __shared__ u32 s_sorted[P1E];
    __shared__ unsigned char s_bkt[P1E];
    int t = threadIdx.x;
    int blk = blockIdx.x;
    if (blk >= NBK) {
        int cb = blk - NBK;
        if (cb < NB_CVTX) {
            int i = (cb * 256 + t) * 4;
            if (i < NN * FIN) {
                float4 f = *(const float4*)(x + i);
                ushort4 o = {f2bf(f.x), f2bf(f.y), f2bf(f.z), f2bf(f.w)};
                *(ushort4*)(xb + i) = o;
            }
        } else {
            // cvt_w: 64 iterations of 256 threads covers 12288+8192
            for (int i = t; i < FH * FIN + FC * FH; i += 256) {
                if (i < FH * FIN) {                   // W1t[128][96] from W1[96][128]
                    int n = i / FIN, k = i % FIN;
                    W1t[i] = f2bf(W1[k * FH + n]);
                } else {                              // W2t[64][128] from W2[128][64]
                    int j = i - FH * FIN;
                    int n = j / FH, k = j % FH;
                    W2t[j] = f2bf(W2[k * FC + n]);
                }
            }
        }
        return;
    }
    int e0 = blk * P1E;
    int n = NE - e0; if (n > P1E) n = P1E;
    s_hist[t] = 0;
    __syncthreads();
    u32 rp[16]; int rb[16];
#pragma unroll
    for (int j = 0; j < 16; j++) {
        int i = j * 256 + t;
        rb[j] = -1;
        if (i < n) {
            int s = srcs[e0 + i], d = dsts[e0 + i];
            int b = d >> BLOW;
            rb[j] = b;
            rp[j] = ((u32)(d & ((1 << BLOW) - 1)) << 17) | (u32)s;
            atomicAdd(&s_hist[b], 1);
        }
    }
    __syncthreads();
    int ct = s_hist[t];
    s_base[t] = ct;
    __syncthreads();
    for (int off = 1; off < 256; off <<= 1) {
        int v = (t >= off) ? s_base[t - off] : 0;
        __syncthreads();
        s_base[t] += v;
        __syncthreads();
    }
    int excl = s_base[t] - ct;
    __syncthreads();
    s_base[t] = excl;
    s_cur[t] = excl;
    if (t < NBK) s_gbase[t] = (ct > 0) ? atomicAdd(&bucket_cursor[t], ct) : 0;
    __syncthreads();
#pragma unroll
    for (int j = 0; j < 16; j++) {
        if (rb[j] >= 0) {
            int r = atomicAdd(&s_cur[rb[j]], 1);
            s_sorted[r] = rp[j];
            s_bkt[r] = (unsigned char)rb[j];
        }
    }
    __syncthreads();
    for (int i = t; i < n; i += 256) {
        int b = s_bkt[i];
        int gpos = s_gbase[b] + (i - s_base[b]);
        if (gpos < BCAP)
            bucket_data[(size_t)b * BCAP + gpos] = s_sorted[i];
    }
}

// ---------- per-bucket counting sort -> CSR + row_start + dinv ----------
__global__ __launch_bounds__(256) void k_csr(const int* __restrict__ bucket_cursor,
                                             const u32* __restrict__ bucket_data,
                                             int* __restrict__ row_start,
                                             float* __restrict__ dinv,
                                             int* __restrict__ src_sorted) {
    __shared__ int s_c[256];
    __shared__ int s_cnt[512];
    __shared__ int s_ps[256];
    __shared__ int s_off[512];
    __shared__ int s_cur[512];
    __shared__ u32 s_edges[BCAP];
    int t = threadIdx.x;
    int b = blockIdx.x;
    int nbe = bucket_cursor[b];
    if (nbe > BCAP) nbe = BCAP;
    s_c[t] = (t < NBK) ? bucket_cursor[t] : 0;
    __syncthreads();
    for (int off = 1; off < 256; off <<= 1) {
        int v = (t >= off) ? s_c[t - off] : 0;
        __syncthreads();
        s_c[t] += v;
        __syncthreads();
    }
    int bbase = s_c[b] - nbe;
    s_cnt[t] = 0; s_cnt[t + 256] = 0;
    __syncthreads();
    for (int i = t; i < nbe; i += 256) {
        u32 p = bucket_data[(size_t)b * BCAP + i];
        s_edges[i] = p;
        atomicAdd(&s_cnt[p >> 17], 1);
    }
    __syncthreads();
    int c0 = s_cnt[2 * t], c1 = s_cnt[2 * t + 1];
    s_ps[t] = c0 + c1;
    __syncthreads();
    for (int off = 1; off < 256; off <<= 1) {
        int v = (t >= off) ? s_ps[t - off] : 0;
        __syncthreads();
        s_ps[t] += v;
        __syncthreads();
    }
    int pexcl = s_ps[t] - (c0 + c1);
    s_off[2 * t] = pexcl;          s_cur[2 * t] = pexcl;
    s_off[2 * t + 1] = pexcl + c0; s_cur[2 * t + 1] = pexcl + c0;
    __syncthreads();
#pragma unroll
    for (int k = 0; k < 2; k++) {
        int ld = k * 256 + t;
        int gd = b * 512 + ld;
        if (gd < NN) {
            row_start[gd] = bbase + s_off[ld];
            dinv[gd] = rsqrtf((float)s_cnt[ld] + 1.0f);
        }
    }
    if (b == 0 && t == 0) row_start[NN] = NE;
    for (int i = t; i < nbe; i += 256) {
        u32 p = s_edges[i];
        int d = p >> 17;
        int r = atomicAdd(&s_cur[d], 1);
        src_sorted[bbase + r] = (int)(p & 0x1FFFFu);
    }
}

// ---------- aggregation layer 1 (CSR, no atomics, unroll-2) ----------
__global__ void k_agg1(const u16* __restrict__ xb, const float* __restrict__ dinv,
                       const int* __restrict__ row_start, const int* __restrict__ src_sorted,
                       u16* __restrict__ aggx) {
    int tid = blockIdx.x * 256 + threadIdx.x;
    int dst = tid / 12, q = tid % 12;  // 12 chunks of 8 bf16 = 96 feats
    if (dst >= NN) return;
    int rs = row_start[dst], re = row_start[dst + 1];
    float dv = dinv[dst];
    float acc[8], v0[8], v1[8];
    load8f(xb + (size_t)dst * FIN + q * 8, acc);
#pragma unroll
    for (int j = 0; j < 8; j++) acc[j] *= dv;  // self-loop term
    int e = rs;
    for (; e + 1 < re; e += 2) {
        int s0 = src_sorted[e], s1 = src_sorted[e + 1];
        float d0 = dinv[s0], d1 = dinv[s1];
        load8f(xb + (size_t)s0 * FIN + q * 8, v0);
        load8f(xb + (size_t)s1 * FIN + q * 8, v1);
#pragma unroll
        for (int j = 0; j < 8; j++) acc[j] += v0[j] * d0 + v1[j] * d1;
    }
    if (e < re) {
        int s0 = src_sorted[e];
        float d0 = dinv[s0];
        load8f(xb + (size_t)s0 * FIN + q * 8, v0);
#pragma unroll
        for (int j = 0; j < 8; j++) acc[j] += v0[j] * d0;
    }
#pragma unroll
    for (int j = 0; j < 8; j++) acc[j] *= dv;
    store8bf(aggx + (size_t)dst * FIN + q * 8, acc);
}

// ---------- fused GEMM1+GEMM2: emb = relu(aggx@W1+b1) [fp32], zb = emb@W2 [bf16] ----------
#define LDSW 136  // 128 + 8 pad (16B-aligned rows, <=4-way ds_read_b128 conflict)
__global__ __launch_bounds__(128) void k_gemm12(const u16* __restrict__ aggx,
                                                const u16* __restrict__ W1t,
                                                const float* __restrict__ b1,
                                                const u16* __restrict__ W2t,
                                                float* __restrict__ emb,
                                                u16* __restrict__ zb) {
    __shared__ u16 sh[2][16 * LDSW];
    int wid = threadIdx.x >> 6, lane = threadIdx.x & 63;
    int wave = blockIdx.x * 2 + wid;
    int row0 = wave << 4;
    int m = lane & 15, quad = lane >> 4;
    f32x4 acc[8] = {{0,0,0,0},{0,0,0,0},{0,0,0,0},{0,0,0,0},
                    {0,0,0,0},{0,0,0,0},{0,0,0,0},{0,0,0,0}};
#pragma unroll
    for (int kt = 0; kt < 3; kt++) {
        bf16x8 a = *(const bf16x8*)(const void*)(aggx + (size_t)(row0 + m) * FIN + kt * 32 + quad * 8);
#pragma unroll
        for (int nt = 0; nt < 8; nt++) {
            bf16x8 b = *(const bf16x8*)(const void*)(W1t + (size_t)(nt * 16 + m) * FIN + kt * 32 + quad * 8);
            acc[nt] = __builtin_amdgcn_mfma_f32_16x16x32_bf16(a, b, acc[nt], 0, 0, 0);
        }
    }
    u16* tile = sh[wid];
#pragma unroll
    for (int nt = 0; nt < 8; nt++) {
        int c = nt * 16 + m;
        float bias = b1[c];
#pragma unroll
        for (int i = 0; i < 4; i++) {
            int r = quad * 4 + i;
            float val = acc[nt][i] + bias;
            val = val > 0.0f ? val : 0.0f;
            emb[(size_t)(row0 + r) * FH + c] = val;
            tile[r * LDSW + c] = f2bf(val);
        }
    }
    __syncthreads();
    f32x4 zacc[4] = {{0,0,0,0},{0,0,0,0},{0,0,0,0},{0,0,0,0}};
#pragma unroll
    for (int kt = 0; kt < 4; kt++) {
        bf16x8 a = *(const bf16x8*)(const void*)(tile + m * LDSW + kt * 32 + quad * 8);
#pragma unroll
        for (int nt = 0; nt < 4; nt++) {
            bf16x8 b = *(const bf16x8*)(const void*)(W2t + (size_t)(nt * 16 + m) * FH + kt * 32 + quad * 8);
            zacc[nt] = __builtin_amdgcn_mfma_f32_16x16x32_bf16(a, b, zacc[nt], 0, 0, 0);
        }
    }
#pragma unroll
    for (int nt = 0; nt < 4; nt++) {
        int c = nt * 16 + m;
#pragma unroll
        for (int i = 0; i < 4; i++) {
            int r = row0 + quad * 4 + i;
            zb[(size_t)r * FC + c] = f2bf(zacc[nt][i]);
        }
    }
}

// ---------- fused agg layer 2 + bias + log_softmax: thread-per-(dst, 8-chunk) ----------
// 8 consecutive lanes cover one dst's 64 features; shfl_xor(1,2,4) reduces in-group.
__global__ void k_agg2lsm(const u16* __restrict__ zb, const float* __restrict__ dinv,
                          const int* __restrict__ row_start, const int* __restrict__ src_sorted,
                          const float* __restrict__ b2, float* __restrict__ logits) {
    int tid = blockIdx.x * 256 + threadIdx.x;
    int dst = tid >> 3, q = tid & 7;
    if (dst >= NN) return;
    int rs = row_start[dst], re = row_start[dst + 1];
    float dv = dinv[dst];
    float acc[8], v0[8], v1[8];
    load8f(zb + (size_t)dst * FC + q * 8, acc);
#pragma unroll
    for (int j = 0; j < 8; j++) acc[j] *= dv;
    int e = rs;
    for (; e + 1 < re; e += 2) {
        int s0 = src_sorted[e], s1 = src_sorted[e + 1];
        float d0 = dinv[s0], d1 = dinv[s1];
        load8f(zb + (size_t)s0 * FC + q * 8, v0);
        load8f(zb + (size_t)s1 * FC + q * 8, v1);
#pragma unroll
        for (int j = 0; j < 8; j++) acc[j] += v0[j] * d0 + v1[j] * d1;
    }
    if (e < re) {
        int s0 = src_sorted[e];
        float d0 = dinv[s0];
        load8f(zb + (size_t)s0 * FC + q * 8, v0);
#pragma unroll
        for (int j = 0; j < 8; j++) acc[j] += v0[j] * d0;
    }
#pragma unroll
    for (int j = 0; j < 8; j++) acc[j] = acc[j] * dv + b2[q * 8 + j];
    // log-softmax over 64 = 8 local + 8 lanes
    float mx = acc[0];
#pragma unroll
    for (int j = 1; j < 8; j++) mx = fmaxf(mx, acc[j]);
#pragma unroll
    for (int d = 1; d < 8; d <<= 1) mx = fmaxf(mx, __shfl_xor(mx, d, 64));
    float s = 0.0f;
#pragma unroll
    for (int j = 0; j < 8; j++) s += expf(acc[j] - mx);
#pragma unroll
    for (int d = 1; d < 8; d <<= 1) s += __shfl_xor(s, d, 64);
    float lse = mx + logf(s);
    float4 o0 = {acc[0] - lse, acc[1] - lse, acc[2] - lse, acc[3] - lse};
    float4 o1 = {acc[4] - lse, acc[5] - lse, acc[6] - lse, acc[7] - lse};
    *(float4*)(logits + (size_t)dst * FC + q * 8) = o0;
    *(float4*)(logits + (size_t)dst * FC + q * 8 + 4) = o1;
}

extern "C" void kernel_launch(void* const* d_in, const int* in_sizes, int n_in,
                              void* d_out, int out_size, void* d_ws, size_t ws_size,
                              hipStream_t stream) {
    const float* x  = (const float*)d_in[0];
    const float* W1 = (const float*)d_in[1];
    const float* b1 = (const float*)d_in[2];
    const float* W2 = (const float*)d_in[3];
    const float* b2 = (const float*)d_in[4];
    const int* ei   = (const int*)d_in[5];
    const int* srcs = ei;
    const int* dsts = ei + NE;

    float* logits = (float*)d_out;                    // [N,64]
    float* emb    = (float*)d_out + (size_t)NN * FC;  // [N,128] fp32

    char* w = (char*)d_ws;
    float* dinv       = (float*)w; w += 400000;
    int*   row_start  = (int*)w;   w += 400128;  // N+1 ints, padded
    int*   src_sorted = (int*)w;   w += 3200000;
    int*   bucket_cursor = (int*)w; w += 1024;
    u16*   xb         = (u16*)w;   w += 19200000;
    u16*   aggx       = (u16*)w;   w += 19200000;
    u16*   W1t        = (u16*)w;   w += 24576;
    u16*   W2t        = (u16*)w;   w += 16384;
    u16*   zb         = (u16*)w;   w += 12800000;
    // bucket_data overlays aggx (dead before k_agg1 writes aggx)
    u32*   bucket_data = (u32*)aggx;

    hipMemsetAsync(bucket_cursor, 0, NBK * 4, stream);
    k_prep<<<NBK + NB_CVTX + 1, 256, 0, stream>>>(srcs, dsts, bucket_cursor, bucket_data,
                                                  x, xb, W1, W2, W1t, W2t);
    k_csr<<<NBK, 256, 0, stream>>>(bucket_cursor, bucket_data, row_start, dinv, src_sorted);
    k_agg1<<<(NN * 12 + 255) / 256, 256, 0, stream>>>(xb, dinv, row_start, src_sorted, aggx);
    k_gemm12<<<NN / 32, 128, 0, stream>>>(aggx, W1t, b1, W2t, emb, zb);
    k_agg2lsm<<<(NN * 8 + 255) / 256, 256, 0, stream>>>(zb, dinv, row_start, src_sorted, b2, logits);
}